// Round 11
// baseline (182.007 us; speedup 1.0000x reference)
//
#include <hip/hip_runtime.h>
#include <hip/hip_bf16.h>

#define IN_F 8192
#define OUT_F 8192
#define BATCH 64
#define KSPLIT 16

typedef __attribute__((ext_vector_type(8))) short  bf16x8_t;  // 8 bf16 (4 VGPRs)
typedef __attribute__((ext_vector_type(8))) ushort u16x8_t;   // 16B store unit
typedef __attribute__((ext_vector_type(4))) float  f32x4_t;   // MFMA accumulator

// ---------------------------------------------------------------------------
// x fp32 [64][8192] -> xb bf16, fragment-major: xb[(k8*64 + row)*8 + j]
// ---------------------------------------------------------------------------
__global__ void wol_xconv(const float* __restrict__ x,
                          ushort* __restrict__ xb) {
    int g = blockIdx.x * 256 + threadIdx.x;   // 65536 threads
    int k8  = g & 1023;
    int row = g >> 10;
    const float4* src = (const float4*)&x[row * IN_F + k8 * 8];
    float4 a = src[0], b = src[1];
    float f[8] = {a.x, a.y, a.z, a.w, b.x, b.y, b.z, b.w};
    union { ushort u[8]; bf16x8_t v; } o;
#pragma unroll
    for (int j = 0; j < 8; ++j) {
        __hip_bfloat16 hb = __float2bfloat16(f[j]);
        o.u[j] = *reinterpret_cast<ushort*>(&hb);
    }
    *(bf16x8_t*)&xb[((size_t)k8 * 64 + row) * 8] = o.v;
}

// ---------------------------------------------------------------------------
// Fused split-K GEMM: R10's proven K-loop + last-block-per-nt reduction.
// Grid: 32 N-tiles x 16 K-splits = 512 blocks x 512 thr (2 blocks/CU).
// Every block: compute -> store bf16 partial -> __threadfence -> ticket.
// The 16th block of an nt re-reads the 15 peer partials (L2-hot), adds its
// OWN accumulator bf16-rounded (so the result is identical no matter which
// block is last -> deterministic), adds bias, writes out once.
// Counters zeroed each call by a captured hipMemsetAsync.
// ---------------------------------------------------------------------------
__global__ void __launch_bounds__(512, 4)
wol_mfma(const int*    __restrict__ qw,
         const int*    __restrict__ qz,
         const float*  __restrict__ sc,
         const ushort* __restrict__ xb,
         ushort*       __restrict__ part,
         const float*  __restrict__ bias,
         float*        __restrict__ out,
         unsigned*     __restrict__ cnt) {
    const int nt   = blockIdx.x & 31;
    const int ks   = blockIdx.x >> 5;
    const int wid  = threadIdx.x >> 6;
    const int lane = threadIdx.x & 63;
    const int ln   = lane & 15;
    const int kb   = lane >> 4;                 // k-subblock 0..3
    const int colbase = nt * 256 + wid * 32;    // wave's 32 columns
    const int k0      = ks * 512;               // block K range (4 groups)
    const int gbase   = k0 >> 7;
    const int qrowb   = k0 >> 3;

    // ---- group-0 prefetch (in flight across LDS staging + barrier) ----
    unsigned qc[4][2]; float svc[2]; unsigned zwc[2];
#pragma unroll
    for (int kt = 0; kt < 4; ++kt)
#pragma unroll
        for (int nj = 0; nj < 2; ++nj)
            qc[kt][nj] = (unsigned)qw[(size_t)(qrowb + kt * 4 + kb) * OUT_F +
                                      colbase + nj * 16 + ln];
#pragma unroll
    for (int nj = 0; nj < 2; ++nj) {
        const int c = colbase + nj * 16 + ln;
        svc[nj] = sc[gbase * OUT_F + c];
        zwc[nj] = (unsigned)qz[gbase * (OUT_F / 8) + (c >> 3)];
    }
    __builtin_amdgcn_sched_barrier(0);          // pin group-0 loads here

    // ---- stage block's A fragments: 64 qrows x 64 rows x 8 bf16 = 64KB ----
    __shared__ ushort lds_x[64 * 64 * 8];
    {
        const bf16x8_t* src = (const bf16x8_t*)xb + (size_t)ks * 4096;
        bf16x8_t*       dst = (bf16x8_t*)lds_x;
#pragma unroll
        for (int i = 0; i < 8; ++i)
            dst[i * 512 + threadIdx.x] = src[i * 512 + threadIdx.x];
    }
    __syncthreads();

    f32x4_t acc[4][2];
#pragma unroll
    for (int mi = 0; mi < 4; ++mi)
#pragma unroll
        for (int nj = 0; nj < 2; ++nj) acc[mi][nj] = (f32x4_t)0.0f;

#pragma unroll 1
    for (int g = 0; g < 4; ++g) {               // real loop, I$-fit body
        // ---- prefetch group g+1 BEFORE computing group g, pinned ----
        unsigned qn[4][2]; float svn[2]; unsigned zwn[2];
        if (g < 3) {
            const int qrow1 = qrowb + (g + 1) * 16;
#pragma unroll
            for (int kt = 0; kt < 4; ++kt)
#pragma unroll
                for (int nj = 0; nj < 2; ++nj)
                    qn[kt][nj] = (unsigned)qw[(size_t)(qrow1 + kt * 4 + kb) * OUT_F +
                                              colbase + nj * 16 + ln];
#pragma unroll
            for (int nj = 0; nj < 2; ++nj) {
                const int c = colbase + nj * 16 + ln;
                svn[nj] = sc[(gbase + g + 1) * OUT_F + c];
                zwn[nj] = (unsigned)qz[(gbase + g + 1) * (OUT_F / 8) + (c >> 3)];
            }
            __builtin_amdgcn_sched_barrier(0);  // loads stay ABOVE the compute
        }

        float s[2], dz[2];
#pragma unroll
        for (int nj = 0; nj < 2; ++nj) {
            const unsigned zp = ((zwc[nj] >> ((ln & 7) * 4)) + 1u) & 15u;  // zp-1 stored
            s[nj]  = svc[nj];
            dz[nj] = -(float)zp * svc[nj];      // w = nib*s + dz
        }

#pragma unroll
        for (int kt = 0; kt < 4; ++kt) {        // 4 K-steps of 32
            const int lrow = g * 16 + kt * 4 + kb;   // local qrow 0..63
            bf16x8_t af[4];
#pragma unroll
            for (int mi = 0; mi < 4; ++mi)
                af[mi] = *(const bf16x8_t*)&lds_x[(lrow * 64 + mi * 16 + ln) * 8];
#pragma unroll
            for (int nj = 0; nj < 2; ++nj) {
                const unsigned qv  = qc[kt][nj];
                const unsigned qlo = qv & 0x0F0F0F0Fu;         // nibbles 0,2,4,6
                const unsigned qhi = (qv >> 4) & 0x0F0F0F0Fu;  // nibbles 1,3,5,7
                union { ushort u[8]; bf16x8_t v; } bu;
#pragma unroll
                for (int b = 0; b < 4; ++b) {
                    const float fe = (float)((qlo >> (8 * b)) & 0xFFu);  // v_cvt_f32_ubyteN
                    const float fo = (float)((qhi >> (8 * b)) & 0xFFu);
                    const float we = fe * s[nj] + dz[nj];
                    const float wo = fo * s[nj] + dz[nj];
                    __hip_bfloat16 he = __float2bfloat16(we);
                    __hip_bfloat16 ho = __float2bfloat16(wo);
                    bu.u[2 * b]     = *reinterpret_cast<ushort*>(&he);
                    bu.u[2 * b + 1] = *reinterpret_cast<ushort*>(&ho);
                }
#pragma unroll
                for (int mi = 0; mi < 4; ++mi)
                    acc[mi][nj] = __builtin_amdgcn_mfma_f32_16x16x32_bf16(
                        af[mi], bu.v, acc[mi][nj], 0, 0, 0);
            }
        }

        if (g < 3) {                            // rotate prefetch buffers
#pragma unroll
            for (int kt = 0; kt < 4; ++kt)
#pragma unroll
                for (int nj = 0; nj < 2; ++nj) qc[kt][nj] = qn[kt][nj];
#pragma unroll
            for (int nj = 0; nj < 2; ++nj) { svc[nj] = svn[nj]; zwc[nj] = zwn[nj]; }
        }
    }

    // ---- store own bf16 partial (fragment-major, one 64B store) ----
    union { ushort u[32]; u16x8_t v8[4]; } ob;
#pragma unroll
    for (int mi = 0; mi < 4; ++mi)
#pragma unroll
        for (int nj = 0; nj < 2; ++nj)
#pragma unroll
            for (int j = 0; j < 4; ++j) {
                __hip_bfloat16 h = __float2bfloat16(acc[mi][nj][j]);
                ob.u[(mi * 2 + nj) * 4 + j] = *reinterpret_cast<ushort*>(&h);
            }
    u16x8_t* pbase = (u16x8_t*)part;
    const size_t myoff = ((size_t)(ks * 32 + nt) * 512 + threadIdx.x) * 4;
#pragma unroll
    for (int i = 0; i < 4; ++i) pbase[myoff + i] = ob.v8[i];

    // ---- last-block-per-nt reduction ----
    __threadfence();                            // release own partial
    __shared__ unsigned ticket_s;
    if (threadIdx.x == 0) ticket_s = atomicAdd(&cnt[nt], 1u);
    __syncthreads();
    if (ticket_s != KSPLIT - 1) return;
    __threadfence();                            // acquire peers' partials

    float sred[32];
#pragma unroll
    for (int e = 0; e < 32; ++e) sred[e] = 0.0f;
#pragma unroll 1
    for (int k2 = 0; k2 < KSPLIT; ++k2) {       // fixed order -> deterministic
        if (k2 == ks) {
#pragma unroll
            for (int e = 0; e < 32; ++e) {
                union { unsigned b; float f; } cv;
                cv.b = ((unsigned)ob.u[e]) << 16;
                sred[e] += cv.f;
            }
        } else {
            const size_t off = ((size_t)(k2 * 32 + nt) * 512 + threadIdx.x) * 4;
#pragma unroll
            for (int i = 0; i < 4; ++i) {
                const u16x8_t p = pbase[off + i];
#pragma unroll
                for (int e = 0; e < 8; ++e) {
                    union { unsigned b; float f; } cv;
                    cv.b = ((unsigned)(ushort)p[e]) << 16;
                    sred[i * 8 + e] += cv.f;
                }
            }
        }
    }
#pragma unroll
    for (int mi = 0; mi < 4; ++mi)
#pragma unroll
        for (int nj = 0; nj < 2; ++nj)
#pragma unroll
            for (int j = 0; j < 4; ++j) {
                const int row = mi * 16 + kb * 4 + j;      // C/D layout (m89)
                const int col = colbase + nj * 16 + ln;
                out[(size_t)row * OUT_F + col] =
                    sred[(mi * 2 + nj) * 4 + j] + bias[col];
            }
}

extern "C" void kernel_launch(void* const* d_in, const int* in_sizes, int n_in,
                              void* d_out, int out_size, void* d_ws, size_t ws_size,
                              hipStream_t stream) {
    const float* x    = (const float*)d_in[0];
    const int*   qw   = (const int*)d_in[1];
    const int*   qz   = (const int*)d_in[2];
    const float* sc   = (const float*)d_in[3];
    const float* bias = (const float*)d_in[4];
    float* out = (float*)d_out;

    ushort*   xb  = (ushort*)d_ws;                          // 1 MiB bf16 acts
    ushort*   prt = (ushort*)((char*)d_ws + (2u << 20));    // 16 MiB partials
    unsigned* cnt = (unsigned*)((char*)d_ws + (20u << 20)); // 32 tickets

    (void)in_sizes; (void)n_in; (void)ws_size; (void)out_size;

    hipMemsetAsync(cnt, 0, 32 * sizeof(unsigned), stream);  // reset tickets
    wol_xconv<<<256, 256, 0, stream>>>(x, xb);
    wol_mfma<<<512, 512, 0, stream>>>(qw, qz, sc, xb, prt, bias, out, cnt);
}

// Round 12
// 31.295 us; speedup vs baseline: 5.8158x; 5.8158x over previous
//
#include <hip/hip_runtime.h>
#include <hip/hip_bf16.h>

#define IN_F 8192
#define OUT_F 8192
#define BATCH 64
#define KSPLIT 8

typedef __attribute__((ext_vector_type(8))) short  bf16x8_t;  // 8 bf16 (4 VGPRs)
typedef __attribute__((ext_vector_type(8))) ushort u16x8_t;   // 16B store unit
typedef __attribute__((ext_vector_type(4))) float  f32x4_t;   // MFMA accumulator

// ---------------------------------------------------------------------------
// x fp32 [64][8192] -> xb bf16, fragment-major: xb[(k8*64 + row)*8 + j]
// ---------------------------------------------------------------------------
__global__ void wol_xconv(const float* __restrict__ x,
                          ushort* __restrict__ xb) {
    int g = blockIdx.x * 256 + threadIdx.x;   // 65536 threads
    int k8  = g & 1023;
    int row = g >> 10;
    const float4* src = (const float4*)&x[row * IN_F + k8 * 8];
    float4 a = src[0], b = src[1];
    float f[8] = {a.x, a.y, a.z, a.w, b.x, b.y, b.z, b.w};
    union { ushort u[8]; bf16x8_t v; } o;
#pragma unroll
    for (int j = 0; j < 8; ++j) {
        __hip_bfloat16 hb = __float2bfloat16(f[j]);
        o.u[j] = *reinterpret_cast<ushort*>(&hb);
    }
    *(bf16x8_t*)&xb[((size_t)k8 * 64 + row) * 8] = o.v;
}

// ---------------------------------------------------------------------------
// Stage A: MFMA GEMM, in-register dequant, A staged in LDS, no atomics.
// KSPLIT=8: grid 32 N-tiles x 8 K-splits = 256 blocks x 512 thr
//           = 1 block/CU, 128 KB LDS holds the block's FULL 1024-K A-slice
//           (staged once, single barrier, no restage).
// Wave w owns cols [nt*256 + w*32), 8 quant groups of 128 K.
// Cross-group q/scale/zero register prefetch (pinned with sched_barrier)
// keeps loads in flight. Partials: bf16 fragment-major, one 64B store.
// ---------------------------------------------------------------------------
__global__ void __launch_bounds__(512, 4)
wol_mfma(const int*    __restrict__ qw,
         const int*    __restrict__ qz,
         const float*  __restrict__ sc,
         const ushort* __restrict__ xb,
         ushort*       __restrict__ part) {
    const int nt   = blockIdx.x & 31;
    const int ks   = blockIdx.x >> 5;           // 0..7
    const int wid  = threadIdx.x >> 6;
    const int lane = threadIdx.x & 63;
    const int ln   = lane & 15;
    const int kb   = lane >> 4;                 // k-subblock 0..3
    const int colbase = nt * 256 + wid * 32;    // wave's 32 columns
    const int k0      = ks * 1024;              // block K range (8 groups)
    const int gbase   = k0 >> 7;
    const int qrowb   = k0 >> 3;                // 128 qrows per block

    // ---- group-0 prefetch (in flight across LDS staging + barrier) ----
    unsigned qc[4][2]; float svc[2]; unsigned zwc[2];
#pragma unroll
    for (int kt = 0; kt < 4; ++kt)
#pragma unroll
        for (int nj = 0; nj < 2; ++nj)
            qc[kt][nj] = (unsigned)qw[(size_t)(qrowb + kt * 4 + kb) * OUT_F +
                                      colbase + nj * 16 + ln];
#pragma unroll
    for (int nj = 0; nj < 2; ++nj) {
        const int c = colbase + nj * 16 + ln;
        svc[nj] = sc[gbase * OUT_F + c];
        zwc[nj] = (unsigned)qz[gbase * (OUT_F / 8) + (c >> 3)];
    }
    __builtin_amdgcn_sched_barrier(0);          // pin group-0 loads here

    // ---- stage block's A slice: 128 qrows x 64 rows x 8 bf16 = 128 KB ----
    __shared__ ushort lds_x[128 * 64 * 8];
    {
        const bf16x8_t* src = (const bf16x8_t*)xb + (size_t)ks * 8192;
        bf16x8_t*       dst = (bf16x8_t*)lds_x;
#pragma unroll
        for (int i = 0; i < 16; ++i)
            dst[i * 512 + threadIdx.x] = src[i * 512 + threadIdx.x];
    }
    __syncthreads();

    f32x4_t acc[4][2];
#pragma unroll
    for (int mi = 0; mi < 4; ++mi)
#pragma unroll
        for (int nj = 0; nj < 2; ++nj) acc[mi][nj] = (f32x4_t)0.0f;

#pragma unroll 1
    for (int g = 0; g < 8; ++g) {               // 8 quant groups of 128 K
        // ---- prefetch group g+1 BEFORE computing group g, pinned ----
        unsigned qn[4][2]; float svn[2]; unsigned zwn[2];
        if (g < 7) {
            const int qrow1 = qrowb + (g + 1) * 16;
#pragma unroll
            for (int kt = 0; kt < 4; ++kt)
#pragma unroll
                for (int nj = 0; nj < 2; ++nj)
                    qn[kt][nj] = (unsigned)qw[(size_t)(qrow1 + kt * 4 + kb) * OUT_F +
                                              colbase + nj * 16 + ln];
#pragma unroll
            for (int nj = 0; nj < 2; ++nj) {
                const int c = colbase + nj * 16 + ln;
                svn[nj] = sc[(gbase + g + 1) * OUT_F + c];
                zwn[nj] = (unsigned)qz[(gbase + g + 1) * (OUT_F / 8) + (c >> 3)];
            }
            __builtin_amdgcn_sched_barrier(0);  // loads stay ABOVE the compute
        }

        float s[2], dz[2];
#pragma unroll
        for (int nj = 0; nj < 2; ++nj) {
            const unsigned zp = ((zwc[nj] >> ((ln & 7) * 4)) + 1u) & 15u;  // zp-1 stored
            s[nj]  = svc[nj];
            dz[nj] = -(float)zp * svc[nj];      // w = nib*s + dz
        }

#pragma unroll
        for (int kt = 0; kt < 4; ++kt) {        // 4 K-steps of 32
            const int lrow = g * 16 + kt * 4 + kb;   // local qrow 0..127
            bf16x8_t af[4];
#pragma unroll
            for (int mi = 0; mi < 4; ++mi)
                af[mi] = *(const bf16x8_t*)&lds_x[(lrow * 64 + mi * 16 + ln) * 8];
#pragma unroll
            for (int nj = 0; nj < 2; ++nj) {
                const unsigned qv  = qc[kt][nj];
                const unsigned qlo = qv & 0x0F0F0F0Fu;         // nibbles 0,2,4,6
                const unsigned qhi = (qv >> 4) & 0x0F0F0F0Fu;  // nibbles 1,3,5,7
                union { ushort u[8]; bf16x8_t v; } bu;
#pragma unroll
                for (int b = 0; b < 4; ++b) {
                    const float fe = (float)((qlo >> (8 * b)) & 0xFFu);  // v_cvt_f32_ubyteN
                    const float fo = (float)((qhi >> (8 * b)) & 0xFFu);
                    const float we = fe * s[nj] + dz[nj];
                    const float wo = fo * s[nj] + dz[nj];
                    __hip_bfloat16 he = __float2bfloat16(we);
                    __hip_bfloat16 ho = __float2bfloat16(wo);
                    bu.u[2 * b]     = *reinterpret_cast<ushort*>(&he);
                    bu.u[2 * b + 1] = *reinterpret_cast<ushort*>(&ho);
                }
#pragma unroll
                for (int mi = 0; mi < 4; ++mi)
                    acc[mi][nj] = __builtin_amdgcn_mfma_f32_16x16x32_bf16(
                        af[mi], bu.v, acc[mi][nj], 0, 0, 0);
            }
        }

        if (g < 7) {                            // rotate prefetch buffers
#pragma unroll
            for (int kt = 0; kt < 4; ++kt)
#pragma unroll
                for (int nj = 0; nj < 2; ++nj) qc[kt][nj] = qn[kt][nj];
#pragma unroll
            for (int nj = 0; nj < 2; ++nj) { svc[nj] = svn[nj]; zwc[nj] = zwn[nj]; }
        }
    }

    // ---- epilogue: bf16 fragment-major partials, one 64B store/thread ----
    union { ushort u[32]; u16x8_t v8[4]; } ob;
#pragma unroll
    for (int mi = 0; mi < 4; ++mi)
#pragma unroll
        for (int nj = 0; nj < 2; ++nj)
#pragma unroll
            for (int j = 0; j < 4; ++j) {
                __hip_bfloat16 h = __float2bfloat16(acc[mi][nj][j]);
                ob.u[(mi * 2 + nj) * 4 + j] = *reinterpret_cast<ushort*>(&h);
            }
    u16x8_t* pb = (u16x8_t*)part + ((size_t)(ks * 32 + nt) * 512 + threadIdx.x) * 4;
#pragma unroll
    for (int i = 0; i < 4; ++i) pb[i] = ob.v8[i];
}

// ---------------------------------------------------------------------------
// Stage B: sum 8 bf16 K-split partials (fragment layout) + bias -> out.
// Each output element written exactly once. 65536 threads.
// ---------------------------------------------------------------------------
__global__ void __launch_bounds__(256)
wol_reduce(const ushort* __restrict__ part,
           const float*  __restrict__ bias,
           float* __restrict__ out) {
    const int u   = blockIdx.x * 256 + threadIdx.x;
    const int v8  = u & 3;               // which ushort8 of the thread's 32
    const int tid = (u >> 2) & 511;      // stage-A thread id
    const int nt  = u >> 11;             // stage-A N-tile

    float s[8];
#pragma unroll
    for (int e = 0; e < 8; ++e) s[e] = 0.0f;
#pragma unroll
    for (int ks = 0; ks < KSPLIT; ++ks) {
        const u16x8_t p = *((const u16x8_t*)part +
                            (((size_t)(ks * 32 + nt) * 512 + tid) * 4 + v8));
#pragma unroll
        for (int e = 0; e < 8; ++e) {
            union { unsigned b; float f; } cv;
            cv.b = ((unsigned)(ushort)p[e]) << 16;   // bf16 -> f32 exact
            s[e] += cv.f;
        }
    }

    const int wid = tid >> 6, lane = tid & 63;
    const int ln = lane & 15, kb = lane >> 4;
#pragma unroll
    for (int e = 0; e < 8; ++e) {
        const int idx = v8 * 8 + e;                  // (mi*2+nj)*4 + j
        const int mi = idx >> 3, nj = (idx >> 2) & 1, j = idx & 3;
        const int row = mi * 16 + kb * 4 + j;
        const int col = nt * 256 + wid * 32 + nj * 16 + ln;
        out[(size_t)row * OUT_F + col] = s[e] + bias[col];
    }
}

extern "C" void kernel_launch(void* const* d_in, const int* in_sizes, int n_in,
                              void* d_out, int out_size, void* d_ws, size_t ws_size,
                              hipStream_t stream) {
    const float* x    = (const float*)d_in[0];
    const int*   qw   = (const int*)d_in[1];
    const int*   qz   = (const int*)d_in[2];
    const float* sc   = (const float*)d_in[3];
    const float* bias = (const float*)d_in[4];
    float* out = (float*)d_out;

    ushort* xb  = (ushort*)d_ws;                         // 1 MiB bf16 activations
    ushort* prt = (ushort*)((char*)d_ws + (2u << 20));   // 8 MiB bf16 partials

    (void)in_sizes; (void)n_in; (void)ws_size; (void)out_size;

    wol_xconv<<<256, 256, 0, stream>>>(x, xb);
    wol_mfma<<<256, 512, 0, stream>>>(qw, qz, sc, xb, prt);
    wol_reduce<<<256, 256, 0, stream>>>(prt, bias, out);
}